// Round 10
// baseline (196.028 us; speedup 1.0000x reference)
//
#include <hip/hip_runtime.h>

// GCN aggregation: out[t] = norm[t] * sum_{e:dst=t} norm[src]*x[src] + EPS*x[t]
// Round 10: (a) partition EPB 2048 + edges in registers (2x blocks -> 2x occupancy,
// no phase-3 re-read; partition was grid-starved at 9.5% occupancy);
// (b) degree-binned node permutation so gather8's uniform wave loop runs to
// ~mean(cnt) instead of max-of-8 (~1.5x fewer masked row loads).
constexpr int D        = 64;
constexpr float EPS    = 0.5f;
constexpr int BKT      = 128;
constexpr int CAPB_MAX = 2048;
constexpr int EPB      = 2048;   // edges per partition block (8/thread in regs)
constexpr int NBMAX    = 1024;
constexpr int MAXOVF   = 65536;
constexpr int NBIN     = 64;     // degree bins for gather ordering

__device__ __forceinline__ unsigned int f2bf(float f) {
    unsigned int u = __float_as_uint(f);
    return (u + 0x7FFFu + ((u >> 16) & 1u)) >> 16;   // RNE to bf16
}
__device__ __forceinline__ float bf2f_lo(unsigned int v) { return __uint_as_float(v << 16); }
__device__ __forceinline__ float bf2f_hi(unsigned int v) { return __uint_as_float(v & 0xFFFF0000u); }

// ---------------- main path ----------------

__global__ void init_kernel(int* __restrict__ curD, int* __restrict__ curS,
                            int* __restrict__ ovf_cnt, int* __restrict__ sovf_cnt,
                            int* __restrict__ binHist, int NB, int capb) {
    int i = blockIdx.x * blockDim.x + threadIdx.x;
    if (i < NB) { curD[i] = i * capb; curS[i] = i * capb; }
    if (i < NBIN) binHist[i] = 0;
    if (i == 0) { *ovf_cnt = 0; *sovf_cnt = 0; }
}

__global__ __launch_bounds__(256)
void partition_kernel(const int* __restrict__ src, const int* __restrict__ dst,
                      int* __restrict__ curD, int* __restrict__ curS,
                      unsigned int* __restrict__ rec, unsigned char* __restrict__ srec,
                      int* __restrict__ ovf_cnt, int* __restrict__ ovf,
                      int* __restrict__ sovf_cnt, int* __restrict__ sovf,
                      int E, int NB, int capb) {
    __shared__ int histD[NBMAX];   // reused as rankD in phase 3
    __shared__ int histS[NBMAX];   // reused as rankS
    __shared__ int startD[NBMAX];
    __shared__ int startS[NBMAX];
    const int base = blockIdx.x * EPB;
    const int tid  = threadIdx.x;
    for (int b = tid; b < NB; b += 256) { histD[b] = 0; histS[b] = 0; }
    __syncthreads();

    int2 ed[EPB / 256];                        // 8 edges/thread in registers
    #pragma unroll
    for (int k = 0; k < EPB / 256; ++k) {
        int e = base + tid + k * 256;          // coalesced
        if (e < E) {
            int s = src[e], t = dst[e];
            ed[k] = make_int2(s, t);
            atomicAdd(&histD[t >> 7], 1);
            atomicAdd(&histS[s >> 7], 1);
        }
    }
    __syncthreads();
    for (int b = tid; b < NB; b += 256) {      // one global reserve atomic per (block,bucket)
        int c = histD[b];
        startD[b] = (c > 0) ? atomicAdd(&curD[b], c) : 0;
        histD[b] = 0;                          // reuse as rank
        int c2 = histS[b];
        startS[b] = (c2 > 0) ? atomicAdd(&curS[b], c2) : 0;
        histS[b] = 0;
    }
    __syncthreads();
    #pragma unroll
    for (int k = 0; k < EPB / 256; ++k) {
        int e = base + tid + k * 256;
        if (e < E) {
            int s = ed[k].x, t = ed[k].y;
            int bD = t >> 7;
            int r  = atomicAdd(&histD[bD], 1);
            int pD = startD[bD] + r;
            if (pD < (bD + 1) * capb) {
                rec[pD] = ((unsigned int)s << 7) | (unsigned int)(t & (BKT - 1));
            } else {
                int i = atomicAdd(ovf_cnt, 1);
                if (i < MAXOVF) { ovf[2 * i] = s; ovf[2 * i + 1] = t; }
            }
            int bS = s >> 7;
            int r2 = atomicAdd(&histS[bS], 1);
            int pS = startS[bS] + r2;
            if (pS < (bS + 1) * capb) {
                srec[pS] = (unsigned char)(s & (BKT - 1));
            } else {
                int i = atomicAdd(sovf_cnt, 1);
                if (i < MAXOVF) sovf[i] = s;
            }
        }
    }
}

// grid = 2*NB. Blocks [0,NB): LDS counting sort of dst-regions -> per-node CSR
// (+ accumulate global in-degree bin histogram for the gather permutation).
// Blocks [NB,2NB): out-degree count from src-regions -> norm + yh = bf16(norm*x).
__global__ __launch_bounds__(256)
void combo_kernel(const unsigned int* __restrict__ rec, const unsigned char* __restrict__ srec,
                  const int* __restrict__ curD, const int* __restrict__ curS,
                  int* __restrict__ csr, int* __restrict__ row_start,
                  int* __restrict__ row_cnt, const float2* __restrict__ x2,
                  float* __restrict__ norm, unsigned int* __restrict__ yh,
                  const int* __restrict__ sovf_cnt, const int* __restrict__ sovf,
                  int* __restrict__ binHist, int n, int NB, int capb) {
    __shared__ unsigned int recs[CAPB_MAX];   // 8 KB
    __shared__ int srcs[CAPB_MAX];            // 8 KB
    __shared__ int hist[BKT];
    __shared__ int scanv[BKT];
    __shared__ int rankb[BKT];
    __shared__ float nrm[BKT];
    __shared__ int lbin[NBIN];
    const int tid = threadIdx.x;

    if (blockIdx.x >= NB) {
        // ---- degcount + norm + yh path ----
        int b = blockIdx.x - NB;
        int cnt = curS[b] - b * capb;
        if (cnt > capb) cnt = capb;
        if (tid < BKT) hist[tid] = 0;
        __syncthreads();
        for (int i = tid; i < cnt; i += 256)
            atomicAdd(&hist[srec[(size_t)b * capb + i]], 1);
        __syncthreads();
        int oc = *sovf_cnt;                    // expected 0
        if (oc > 0) {
            if (oc > MAXOVF) oc = MAXOVF;
            for (int i = tid; i < oc; i += 256) {
                int s = sovf[i];
                if ((s >> 7) == b) atomicAdd(&hist[s & (BKT - 1)], 1);
            }
            __syncthreads();
        }
        if (tid < BKT) {
            int node = b * BKT + tid;
            float nm = rsqrtf(fmaxf((float)hist[tid], 1.0f));
            nrm[tid] = nm;
            if (node < n) norm[node] = nm;
        }
        __syncthreads();
        int nodes = n - b * BKT;
        if (nodes > BKT) nodes = BKT;
        if (nodes < 0) nodes = 0;
        int total = nodes * (D / 2);           // float2 elements in this bucket
        size_t gbase = (size_t)b * BKT * (D / 2);
        for (int i = tid; i < total; i += 256) {   // contiguous -> coalesced
            float2 v = x2[gbase + i];
            float nm = nrm[i >> 5];
            yh[gbase + i] = f2bf(v.x * nm) | (f2bf(v.y * nm) << 16);
        }
        return;
    }

    // ---- sort path ----
    const int b = blockIdx.x;
    int cnt = curD[b] - b * capb;
    if (cnt > capb) cnt = capb;
    for (int i = tid; i < cnt; i += 256) recs[i] = rec[(size_t)b * capb + i];
    if (tid < BKT) hist[tid] = 0;
    if (tid < NBIN) lbin[tid] = 0;
    __syncthreads();
    for (int i = tid; i < cnt; i += 256) atomicAdd(&hist[recs[i] & (BKT - 1)], 1);
    __syncthreads();
    if (tid < BKT) scanv[tid] = hist[tid];
    __syncthreads();
    #pragma unroll
    for (int off = 1; off < BKT; off <<= 1) {          // Hillis-Steele inclusive scan
        int t = 0;
        if (tid < BKT && tid >= off) t = scanv[tid - off];
        __syncthreads();
        if (tid < BKT) scanv[tid] += t;
        __syncthreads();
    }
    if (tid < BKT) {
        int excl = scanv[tid] - hist[tid];
        rankb[tid] = excl;
        int node = b * BKT + tid;
        if (node < n) {
            row_start[node] = b * capb + excl;
            row_cnt[node]   = hist[tid];
            atomicAdd(&lbin[min(hist[tid], NBIN - 1)], 1);   // LDS bin hist
        }
    }
    __syncthreads();
    if (tid < NBIN && lbin[tid] > 0) atomicAdd(&binHist[tid], lbin[tid]);
    for (int i = tid; i < cnt; i += 256) {
        unsigned int v = recs[i];
        int pos = atomicAdd(&rankb[v & (BKT - 1)], 1);
        srcs[pos] = (int)(v >> 7);
    }
    __syncthreads();
    for (int i = tid; i < cnt; i += 256) csr[(size_t)b * capb + i] = srcs[i];
}

// single block: binCursor = exclusive scan of binHist (64 bins)
__global__ void dscan_kernel(const int* __restrict__ binHist, int* __restrict__ binCursor) {
    __shared__ int sh[NBIN];
    int t = threadIdx.x;
    if (t < NBIN) sh[t] = binHist[t];
    __syncthreads();
    if (t == 0) {
        int run = 0;
        for (int i = 0; i < NBIN; ++i) { int v = sh[i]; sh[i] = run; run += v; }
    }
    __syncthreads();
    if (t < NBIN) binCursor[t] = sh[t];
}

// perm: nodes grouped by in-degree bin (stable-ish; order within bin irrelevant)
__global__ __launch_bounds__(1024)
void dperm_kernel(const int* __restrict__ row_cnt, int* __restrict__ binCursor,
                  int* __restrict__ perm, int n) {
    __shared__ int lhist[NBIN];
    __shared__ int lstart[NBIN];
    int tid = threadIdx.x;
    int node = blockIdx.x * 1024 + tid;
    if (tid < NBIN) lhist[tid] = 0;
    __syncthreads();
    int bin = 0;
    if (node < n) {
        bin = min(row_cnt[node], NBIN - 1);
        atomicAdd(&lhist[bin], 1);
    }
    __syncthreads();
    if (tid < NBIN) {
        int c = lhist[tid];
        lstart[tid] = (c > 0) ? atomicAdd(&binCursor[tid], c) : 0;
        lhist[tid] = 0;                        // reuse as rank
    }
    __syncthreads();
    if (node < n) {
        int r = atomicAdd(&lhist[bin], 1);
        perm[lstart[bin] + r] = node;
    }
}

// 8 nodes per wave via degree-sorted perm: oct (8 lanes) x uint4 = one 128B row.
// Wave-max(cnt) ~ mean(cnt) because waves see equal-degree nodes.
__global__ __launch_bounds__(256)
void gather8_kernel(const uint4* __restrict__ yr4, const float4* __restrict__ x4,
                    const int* __restrict__ csr, const int* __restrict__ row_start,
                    const int* __restrict__ row_cnt, const float* __restrict__ norm,
                    const int* __restrict__ perm, float4* __restrict__ out4, int n) {
    int wid  = (blockIdx.x * blockDim.x + threadIdx.x) >> 6;
    int lane = threadIdx.x & 63;
    int fl   = lane & 7;               // uint4 index within row (8 x 16B = 128B)
    int slot = wid * 8 + (lane >> 3);  // oct -> slot
    bool valid = slot < n;
    int node = valid ? perm[slot] : 0; // coalesced (8 consecutive ints per wave)
    int rs  = valid ? row_start[node] : 0;
    int cnt = valid ? row_cnt[node] : 0;
    int m = cnt;
    m = max(m, __shfl_xor(m, 8));
    m = max(m, __shfl_xor(m, 16));
    m = max(m, __shfl_xor(m, 32));
    float a0 = 0.f, a1 = 0.f, a2 = 0.f, a3 = 0.f, a4 = 0.f, a5 = 0.f, a6 = 0.f, a7 = 0.f;
    for (int k = 0; k < m; k += 4) {
        #pragma unroll
        for (int j = 0; j < 4; ++j) {
            int kj = k + j;
            bool take = kj < cnt;
            int s = csr[rs + (take ? kj : 0)];
            s = take ? s : 0;
            uint4 v = yr4[(size_t)s * 8 + fl];
            if (!take) { v.x = 0u; v.y = 0u; v.z = 0u; v.w = 0u; }
            a0 += bf2f_lo(v.x); a1 += bf2f_hi(v.x);
            a2 += bf2f_lo(v.y); a3 += bf2f_hi(v.y);
            a4 += bf2f_lo(v.z); a5 += bf2f_hi(v.z);
            a6 += bf2f_lo(v.w); a7 += bf2f_hi(v.w);
        }
    }
    if (valid) {
        float nt = norm[node];
        size_t base = (size_t)node * 16 + fl * 2;
        float4 xv0 = x4[base], xv1 = x4[base + 1];
        float4 r0, r1;
        r0.x = a0 * nt + EPS * xv0.x;  r0.y = a1 * nt + EPS * xv0.y;
        r0.z = a2 * nt + EPS * xv0.z;  r0.w = a3 * nt + EPS * xv0.w;
        r1.x = a4 * nt + EPS * xv1.x;  r1.y = a5 * nt + EPS * xv1.y;
        r1.z = a6 * nt + EPS * xv1.z;  r1.w = a7 * nt + EPS * xv1.w;
        out4[base] = r0;               // 128B run per oct
        out4[base + 1] = r1;
    }
}

// rare: dst-bucket overflow edges (expected 0)
__global__ void cleanup_kernel(const float* __restrict__ x, const float* __restrict__ norm,
                               const int* __restrict__ ovf_cnt, const int* __restrict__ ovf,
                               float* __restrict__ out) {
    int cnt = *ovf_cnt;
    if (cnt > MAXOVF) cnt = MAXOVF;
    long long total = (long long)cnt * D;
    long long stride = (long long)gridDim.x * blockDim.x;
    for (long long i = blockIdx.x * (long long)blockDim.x + threadIdx.x; i < total; i += stride) {
        int e = (int)(i >> 6), d = (int)(i & 63);
        int s = ovf[2 * e], t = ovf[2 * e + 1];
        atomicAdd(&out[(size_t)t * D + d], norm[s] * norm[t] * x[(size_t)s * D + d]);
    }
}

// ---------------- tiny-ws / big-n fallback (round-1 proven) ----------------

__global__ void fb_hist(const int* __restrict__ src, int* __restrict__ deg, int E) {
    int e = blockIdx.x * blockDim.x + threadIdx.x;
    if (e < E) atomicAdd(&deg[src[e]], 1);
}
__global__ void fb_norm(const int* __restrict__ deg, float* __restrict__ norm, int n) {
    int i = blockIdx.x * blockDim.x + threadIdx.x;
    if (i < n) norm[i] = rsqrtf(fmaxf((float)deg[i], 1.0f));
}
__global__ void fb_init_out(const float4* __restrict__ x, float4* __restrict__ out, int n4) {
    int i = blockIdx.x * blockDim.x + threadIdx.x;
    if (i < n4) {
        float4 v = x[i];
        out[i] = make_float4(v.x * EPS, v.y * EPS, v.z * EPS, v.w * EPS);
    }
}
__global__ void fb_scatter(const float* __restrict__ x, const int* __restrict__ src,
                           const int* __restrict__ dst, const float* __restrict__ norm,
                           float* __restrict__ out, int E) {
    long long tid = (long long)blockIdx.x * blockDim.x + threadIdx.x;
    int e = (int)(tid >> 6), d = (int)(tid & 63);
    if (e < E) {
        int s = src[e], t = dst[e];
        atomicAdd(&out[(size_t)t * D + d], norm[s] * norm[t] * x[(size_t)s * D + d]);
    }
}

// ---------------- launcher ----------------

extern "C" void kernel_launch(void* const* d_in, const int* in_sizes, int n_in,
                              void* d_out, int out_size, void* d_ws, size_t ws_size,
                              hipStream_t stream) {
    const float* x   = (const float*)d_in[0];
    const int*   src = (const int*)d_in[1];
    const int*   dst = (const int*)d_in[2];
    float* out = (float*)d_out;

    const int ND = in_sizes[0];
    const int E  = in_sizes[1];
    const int n  = ND / D;
    const int NB = (n + BKT - 1) / BKT;
    constexpr int B = 256;

    int capb = 0;
    for (int c : {2048, 1792}) {
        size_t need = (size_t)NB * c * 4                // rec (packed u32)
                    + (size_t)NB * c * 4                // csr
                    + (size_t)NB * c                    // srec (u8)
                    + ((size_t)(2 * NB + 127) & ~63ull) * 4
                    + (size_t)n * 4 * 4                 // norm, row_start, row_cnt, perm
                    + (size_t)ND * 2                    // yh
                    + (size_t)(256 + 3 * MAXOVF) * 4;
        if (need <= ws_size) { capb = c; break; }
    }

    if (NB <= NBMAX && capb > 0 && n < (1 << 24)) {
        unsigned int* rec   = (unsigned int*)d_ws;                       // NB*capb u32
        int*   csr          = (int*)(rec + (size_t)NB * capb);           // NB*capb
        unsigned char* srec = (unsigned char*)(csr + (size_t)NB * capb); // NB*capb u8
        int*   curD         = (int*)(srec + (((size_t)NB * capb + 3) & ~3ull)); // NB
        int*   curS         = curD + NB;                                 // NB
        float* norm         = (float*)(curS + ((NB + 63) & ~63));        // n
        int*   row_start    = (int*)(norm + n);                          // n
        int*   row_cnt      = row_start + n;                             // n
        int*   perm         = row_cnt + n;                               // n
        unsigned int* yh    = (unsigned int*)(perm + n);                 // ND/2 u32
        int*   ovf_cnt      = (int*)(yh + ND / 2);                       // [0]
        int*   sovf_cnt     = ovf_cnt + 64;                              // [0]
        int*   binHist      = sovf_cnt + 64;                             // NBIN
        int*   binCursor    = binHist + NBIN;                            // NBIN
        int*   ovf          = binCursor + NBIN;                          // 2*MAXOVF
        int*   sovf         = ovf + 2 * MAXOVF;                          // MAXOVF

        init_kernel<<<(NB + B - 1) / B, B, 0, stream>>>(curD, curS, ovf_cnt, sovf_cnt,
                                                        binHist, NB, capb);
        partition_kernel<<<(E + EPB - 1) / EPB, B, 0, stream>>>(src, dst, curD, curS, rec, srec,
                                                                ovf_cnt, ovf, sovf_cnt, sovf,
                                                                E, NB, capb);
        combo_kernel<<<2 * NB, B, 0, stream>>>(rec, srec, curD, curS, csr, row_start, row_cnt,
                                               (const float2*)x, norm, yh, sovf_cnt, sovf,
                                               binHist, n, NB, capb);
        dscan_kernel<<<1, 64, 0, stream>>>(binHist, binCursor);
        dperm_kernel<<<(n + 1023) / 1024, 1024, 0, stream>>>(row_cnt, binCursor, perm, n);
        gather8_kernel<<<(n + 31) / 32, B, 0, stream>>>((const uint4*)yh, (const float4*)x,
                                                        csr, row_start, row_cnt, norm, perm,
                                                        (float4*)out, n);
        cleanup_kernel<<<64, B, 0, stream>>>(x, norm, ovf_cnt, ovf, out);
    } else {
        int*   deg  = (int*)d_ws;
        float* norm = (float*)d_ws + n;
        hipMemsetAsync(deg, 0, (size_t)n * sizeof(int), stream);
        fb_hist<<<(E + B - 1) / B, B, 0, stream>>>(src, deg, E);
        fb_norm<<<(n + B - 1) / B, B, 0, stream>>>(deg, norm, n);
        fb_init_out<<<(ND / 4 + B - 1) / B, B, 0, stream>>>((const float4*)x, (float4*)out, ND / 4);
        long long total = (long long)E * D;
        fb_scatter<<<(int)((total + B - 1) / B), B, 0, stream>>>(x, src, dst, norm, out, E);
    }
}

// Round 11
// 176.812 us; speedup vs baseline: 1.1087x; 1.1087x over previous
//
#include <hip/hip_runtime.h>

// GCN aggregation: out[t] = norm[t] * sum_{e:dst=t} norm[src]*x[src] + EPS*x[t]
// Round 11: revert R10's degree permutation (it broke gather locality: 32->51us,
// FETCH 134->155MB). Keep R10's partition fix: EPB=2048 with edges cached in
// registers (611 blocks vs 306 -> 2x occupancy on the latency-bound partition,
// and no phase-3 re-read of src/dst). Gather in natural node order (R9-proven).
constexpr int D        = 64;
constexpr float EPS    = 0.5f;
constexpr int BKT      = 128;
constexpr int CAPB_MAX = 2048;
constexpr int EPB      = 2048;   // edges per partition block (8/thread in regs)
constexpr int NBMAX    = 1024;
constexpr int MAXOVF   = 65536;

__device__ __forceinline__ unsigned int f2bf(float f) {
    unsigned int u = __float_as_uint(f);
    return (u + 0x7FFFu + ((u >> 16) & 1u)) >> 16;   // RNE to bf16
}
__device__ __forceinline__ float bf2f_lo(unsigned int v) { return __uint_as_float(v << 16); }
__device__ __forceinline__ float bf2f_hi(unsigned int v) { return __uint_as_float(v & 0xFFFF0000u); }

// ---------------- main path ----------------

__global__ void init_kernel(int* __restrict__ curD, int* __restrict__ curS,
                            int* __restrict__ ovf_cnt, int* __restrict__ sovf_cnt,
                            int NB, int capb) {
    int i = blockIdx.x * blockDim.x + threadIdx.x;
    if (i < NB) { curD[i] = i * capb; curS[i] = i * capb; }
    if (i == 0) { *ovf_cnt = 0; *sovf_cnt = 0; }
}

__global__ __launch_bounds__(256)
void partition_kernel(const int* __restrict__ src, const int* __restrict__ dst,
                      int* __restrict__ curD, int* __restrict__ curS,
                      unsigned int* __restrict__ rec, unsigned char* __restrict__ srec,
                      int* __restrict__ ovf_cnt, int* __restrict__ ovf,
                      int* __restrict__ sovf_cnt, int* __restrict__ sovf,
                      int E, int NB, int capb) {
    __shared__ int histD[NBMAX];   // reused as rankD in phase 3
    __shared__ int histS[NBMAX];   // reused as rankS
    __shared__ int startD[NBMAX];
    __shared__ int startS[NBMAX];
    const int base = blockIdx.x * EPB;
    const int tid  = threadIdx.x;
    for (int b = tid; b < NB; b += 256) { histD[b] = 0; histS[b] = 0; }
    __syncthreads();

    int2 ed[EPB / 256];                        // 8 edges/thread in registers
    #pragma unroll
    for (int k = 0; k < EPB / 256; ++k) {
        int e = base + tid + k * 256;          // coalesced
        if (e < E) {
            int s = src[e], t = dst[e];
            ed[k] = make_int2(s, t);
            atomicAdd(&histD[t >> 7], 1);
            atomicAdd(&histS[s >> 7], 1);
        }
    }
    __syncthreads();
    for (int b = tid; b < NB; b += 256) {      // one global reserve atomic per (block,bucket)
        int c = histD[b];
        startD[b] = (c > 0) ? atomicAdd(&curD[b], c) : 0;
        histD[b] = 0;                          // reuse as rank
        int c2 = histS[b];
        startS[b] = (c2 > 0) ? atomicAdd(&curS[b], c2) : 0;
        histS[b] = 0;
    }
    __syncthreads();
    #pragma unroll
    for (int k = 0; k < EPB / 256; ++k) {
        int e = base + tid + k * 256;
        if (e < E) {
            int s = ed[k].x, t = ed[k].y;
            int bD = t >> 7;
            int r  = atomicAdd(&histD[bD], 1);
            int pD = startD[bD] + r;
            if (pD < (bD + 1) * capb) {
                rec[pD] = ((unsigned int)s << 7) | (unsigned int)(t & (BKT - 1));
            } else {
                int i = atomicAdd(ovf_cnt, 1);
                if (i < MAXOVF) { ovf[2 * i] = s; ovf[2 * i + 1] = t; }
            }
            int bS = s >> 7;
            int r2 = atomicAdd(&histS[bS], 1);
            int pS = startS[bS] + r2;
            if (pS < (bS + 1) * capb) {
                srec[pS] = (unsigned char)(s & (BKT - 1));
            } else {
                int i = atomicAdd(sovf_cnt, 1);
                if (i < MAXOVF) sovf[i] = s;
            }
        }
    }
}

// grid = 2*NB. Blocks [0,NB): LDS counting sort of dst-regions -> per-node CSR.
// Blocks [NB,2NB): out-degree count from src-regions (+ rare sovf entries) ->
// norm + yh = bf16(norm*x) for the bucket's contiguous node range.
__global__ __launch_bounds__(256)
void combo_kernel(const unsigned int* __restrict__ rec, const unsigned char* __restrict__ srec,
                  const int* __restrict__ curD, const int* __restrict__ curS,
                  int* __restrict__ csr, int* __restrict__ row_start,
                  int* __restrict__ row_cnt, const float2* __restrict__ x2,
                  float* __restrict__ norm, unsigned int* __restrict__ yh,
                  const int* __restrict__ sovf_cnt, const int* __restrict__ sovf,
                  int n, int NB, int capb) {
    __shared__ unsigned int recs[CAPB_MAX];   // 8 KB
    __shared__ int srcs[CAPB_MAX];            // 8 KB
    __shared__ int hist[BKT];
    __shared__ int scanv[BKT];
    __shared__ int rankb[BKT];
    __shared__ float nrm[BKT];
    const int tid = threadIdx.x;

    if (blockIdx.x >= NB) {
        // ---- degcount + norm + yh path ----
        int b = blockIdx.x - NB;
        int cnt = curS[b] - b * capb;
        if (cnt > capb) cnt = capb;
        if (tid < BKT) hist[tid] = 0;
        __syncthreads();
        for (int i = tid; i < cnt; i += 256)
            atomicAdd(&hist[srec[(size_t)b * capb + i]], 1);
        __syncthreads();
        int oc = *sovf_cnt;                    // expected 0
        if (oc > 0) {
            if (oc > MAXOVF) oc = MAXOVF;
            for (int i = tid; i < oc; i += 256) {
                int s = sovf[i];
                if ((s >> 7) == b) atomicAdd(&hist[s & (BKT - 1)], 1);
            }
            __syncthreads();
        }
        if (tid < BKT) {
            int node = b * BKT + tid;
            float nm = rsqrtf(fmaxf((float)hist[tid], 1.0f));
            nrm[tid] = nm;
            if (node < n) norm[node] = nm;
        }
        __syncthreads();
        int nodes = n - b * BKT;
        if (nodes > BKT) nodes = BKT;
        if (nodes < 0) nodes = 0;
        int total = nodes * (D / 2);           // float2 elements in this bucket
        size_t gbase = (size_t)b * BKT * (D / 2);
        for (int i = tid; i < total; i += 256) {   // contiguous -> coalesced
            float2 v = x2[gbase + i];
            float nm = nrm[i >> 5];
            yh[gbase + i] = f2bf(v.x * nm) | (f2bf(v.y * nm) << 16);
        }
        return;
    }

    // ---- sort path ----
    const int b = blockIdx.x;
    int cnt = curD[b] - b * capb;
    if (cnt > capb) cnt = capb;
    for (int i = tid; i < cnt; i += 256) recs[i] = rec[(size_t)b * capb + i];
    if (tid < BKT) hist[tid] = 0;
    __syncthreads();
    for (int i = tid; i < cnt; i += 256) atomicAdd(&hist[recs[i] & (BKT - 1)], 1);
    __syncthreads();
    if (tid < BKT) scanv[tid] = hist[tid];
    __syncthreads();
    #pragma unroll
    for (int off = 1; off < BKT; off <<= 1) {          // Hillis-Steele inclusive scan
        int t = 0;
        if (tid < BKT && tid >= off) t = scanv[tid - off];
        __syncthreads();
        if (tid < BKT) scanv[tid] += t;
        __syncthreads();
    }
    if (tid < BKT) {
        int excl = scanv[tid] - hist[tid];
        rankb[tid] = excl;
        int node = b * BKT + tid;
        if (node < n) {
            row_start[node] = b * capb + excl;
            row_cnt[node]   = hist[tid];
        }
    }
    __syncthreads();
    for (int i = tid; i < cnt; i += 256) {
        unsigned int v = recs[i];
        int pos = atomicAdd(&rankb[v & (BKT - 1)], 1);
        srcs[pos] = (int)(v >> 7);
    }
    __syncthreads();
    for (int i = tid; i < cnt; i += 256) csr[(size_t)b * capb + i] = srcs[i];
}

// 8 nodes per wave in NATURAL order (locality: contiguous out writes, sequential
// csr/row_start reads). Oct (8 lanes) x uint4 = one 128B yh row per vmem inst.
// Uniform loop count = wave-max(cnt); out-of-range iterations masked to zero.
__global__ __launch_bounds__(256)
void gather8_kernel(const uint4* __restrict__ yr4, const float4* __restrict__ x4,
                    const int* __restrict__ csr, const int* __restrict__ row_start,
                    const int* __restrict__ row_cnt, const float* __restrict__ norm,
                    float4* __restrict__ out4, int n) {
    int wid  = (blockIdx.x * blockDim.x + threadIdx.x) >> 6;
    int lane = threadIdx.x & 63;
    int fl   = lane & 7;               // uint4 index within row (8 x 16B = 128B)
    int node = wid * 8 + (lane >> 3);  // oct -> node
    bool valid = node < n;
    int rs  = valid ? row_start[node] : 0;
    int cnt = valid ? row_cnt[node] : 0;
    int m = cnt;
    m = max(m, __shfl_xor(m, 8));
    m = max(m, __shfl_xor(m, 16));
    m = max(m, __shfl_xor(m, 32));
    float a0 = 0.f, a1 = 0.f, a2 = 0.f, a3 = 0.f, a4 = 0.f, a5 = 0.f, a6 = 0.f, a7 = 0.f;
    for (int k = 0; k < m; k += 4) {
        #pragma unroll
        for (int j = 0; j < 4; ++j) {
            int kj = k + j;
            bool take = kj < cnt;
            int s = csr[rs + (take ? kj : 0)];
            s = take ? s : 0;
            uint4 v = yr4[(size_t)s * 8 + fl];
            if (!take) { v.x = 0u; v.y = 0u; v.z = 0u; v.w = 0u; }
            a0 += bf2f_lo(v.x); a1 += bf2f_hi(v.x);
            a2 += bf2f_lo(v.y); a3 += bf2f_hi(v.y);
            a4 += bf2f_lo(v.z); a5 += bf2f_hi(v.z);
            a6 += bf2f_lo(v.w); a7 += bf2f_hi(v.w);
        }
    }
    if (valid) {
        float nt = norm[node];
        size_t base = (size_t)node * 16 + fl * 2;
        float4 xv0 = x4[base], xv1 = x4[base + 1];
        float4 r0, r1;
        r0.x = a0 * nt + EPS * xv0.x;  r0.y = a1 * nt + EPS * xv0.y;
        r0.z = a2 * nt + EPS * xv0.z;  r0.w = a3 * nt + EPS * xv0.w;
        r1.x = a4 * nt + EPS * xv1.x;  r1.y = a5 * nt + EPS * xv1.y;
        r1.z = a6 * nt + EPS * xv1.z;  r1.w = a7 * nt + EPS * xv1.w;
        out4[base] = r0;               // coalesced: contiguous 2KB per wave
        out4[base + 1] = r1;
    }
}

// rare: dst-bucket overflow edges (expected 0)
__global__ void cleanup_kernel(const float* __restrict__ x, const float* __restrict__ norm,
                               const int* __restrict__ ovf_cnt, const int* __restrict__ ovf,
                               float* __restrict__ out) {
    int cnt = *ovf_cnt;
    if (cnt > MAXOVF) cnt = MAXOVF;
    long long total = (long long)cnt * D;
    long long stride = (long long)gridDim.x * blockDim.x;
    for (long long i = blockIdx.x * (long long)blockDim.x + threadIdx.x; i < total; i += stride) {
        int e = (int)(i >> 6), d = (int)(i & 63);
        int s = ovf[2 * e], t = ovf[2 * e + 1];
        atomicAdd(&out[(size_t)t * D + d], norm[s] * norm[t] * x[(size_t)s * D + d]);
    }
}

// ---------------- tiny-ws / big-n fallback (round-1 proven) ----------------

__global__ void fb_hist(const int* __restrict__ src, int* __restrict__ deg, int E) {
    int e = blockIdx.x * blockDim.x + threadIdx.x;
    if (e < E) atomicAdd(&deg[src[e]], 1);
}
__global__ void fb_norm(const int* __restrict__ deg, float* __restrict__ norm, int n) {
    int i = blockIdx.x * blockDim.x + threadIdx.x;
    if (i < n) norm[i] = rsqrtf(fmaxf((float)deg[i], 1.0f));
}
__global__ void fb_init_out(const float4* __restrict__ x, float4* __restrict__ out, int n4) {
    int i = blockIdx.x * blockDim.x + threadIdx.x;
    if (i < n4) {
        float4 v = x[i];
        out[i] = make_float4(v.x * EPS, v.y * EPS, v.z * EPS, v.w * EPS);
    }
}
__global__ void fb_scatter(const float* __restrict__ x, const int* __restrict__ src,
                           const int* __restrict__ dst, const float* __restrict__ norm,
                           float* __restrict__ out, int E) {
    long long tid = (long long)blockIdx.x * blockDim.x + threadIdx.x;
    int e = (int)(tid >> 6), d = (int)(tid & 63);
    if (e < E) {
        int s = src[e], t = dst[e];
        atomicAdd(&out[(size_t)t * D + d], norm[s] * norm[t] * x[(size_t)s * D + d]);
    }
}

// ---------------- launcher ----------------

extern "C" void kernel_launch(void* const* d_in, const int* in_sizes, int n_in,
                              void* d_out, int out_size, void* d_ws, size_t ws_size,
                              hipStream_t stream) {
    const float* x   = (const float*)d_in[0];
    const int*   src = (const int*)d_in[1];
    const int*   dst = (const int*)d_in[2];
    float* out = (float*)d_out;

    const int ND = in_sizes[0];
    const int E  = in_sizes[1];
    const int n  = ND / D;
    const int NB = (n + BKT - 1) / BKT;
    constexpr int B = 256;

    int capb = 0;
    for (int c : {2048, 1792}) {
        size_t need = (size_t)NB * c * 4                // rec (packed u32)
                    + (size_t)NB * c * 4                // csr
                    + (size_t)NB * c                    // srec (u8)
                    + ((size_t)(2 * NB + 127) & ~63ull) * 4
                    + (size_t)n * 4 * 3                 // norm, row_start, row_cnt
                    + (size_t)ND * 2                    // yh
                    + (size_t)(128 + 3 * MAXOVF) * 4;
        if (need <= ws_size) { capb = c; break; }
    }

    if (NB <= NBMAX && capb > 0 && n < (1 << 24)) {
        unsigned int* rec   = (unsigned int*)d_ws;                       // NB*capb u32
        int*   csr          = (int*)(rec + (size_t)NB * capb);           // NB*capb
        unsigned char* srec = (unsigned char*)(csr + (size_t)NB * capb); // NB*capb u8
        int*   curD         = (int*)(srec + (((size_t)NB * capb + 3) & ~3ull)); // NB
        int*   curS         = curD + NB;                                 // NB
        float* norm         = (float*)(curS + ((NB + 63) & ~63));        // n
        int*   row_start    = (int*)(norm + n);                          // n
        int*   row_cnt      = row_start + n;                             // n
        unsigned int* yh    = (unsigned int*)(row_cnt + n);              // ND/2 u32
        int*   ovf_cnt      = (int*)(yh + ND / 2);                       // [0]
        int*   sovf_cnt     = ovf_cnt + 64;                              // [0]
        int*   ovf          = sovf_cnt + 64;                             // 2*MAXOVF
        int*   sovf         = ovf + 2 * MAXOVF;                          // MAXOVF

        init_kernel<<<(NB + B - 1) / B, B, 0, stream>>>(curD, curS, ovf_cnt, sovf_cnt, NB, capb);
        partition_kernel<<<(E + EPB - 1) / EPB, B, 0, stream>>>(src, dst, curD, curS, rec, srec,
                                                                ovf_cnt, ovf, sovf_cnt, sovf,
                                                                E, NB, capb);
        combo_kernel<<<2 * NB, B, 0, stream>>>(rec, srec, curD, curS, csr, row_start, row_cnt,
                                               (const float2*)x, norm, yh, sovf_cnt, sovf,
                                               n, NB, capb);
        gather8_kernel<<<(n + 31) / 32, B, 0, stream>>>((const uint4*)yh, (const float4*)x,
                                                        csr, row_start, row_cnt, norm,
                                                        (float4*)out, n);
        cleanup_kernel<<<64, B, 0, stream>>>(x, norm, ovf_cnt, ovf, out);
    } else {
        int*   deg  = (int*)d_ws;
        float* norm = (float*)d_ws + n;
        hipMemsetAsync(deg, 0, (size_t)n * sizeof(int), stream);
        fb_hist<<<(E + B - 1) / B, B, 0, stream>>>(src, deg, E);
        fb_norm<<<(n + B - 1) / B, B, 0, stream>>>(deg, norm, n);
        fb_init_out<<<(ND / 4 + B - 1) / B, B, 0, stream>>>((const float4*)x, (float4*)out, ND / 4);
        long long total = (long long)E * D;
        fb_scatter<<<(int)((total + B - 1) / B), B, 0, stream>>>(x, src, dst, norm, out, E);
    }
}